// Round 2
// baseline (1941.534 us; speedup 1.0000x reference)
//
#include <hip/hip_runtime.h>
#include <hip/hip_bf16.h>

#define LNUM 128
#define NNODES 30000
#define NEDGES 150000
#define NSTEPS 5

// NOTE (r17 discovery): d_out is FLOAT32 (reference is pure jnp.float32).
// Split-f16 numerics: x = hi + lo/2048 -> 3 MFMAs per frag pair, ~f32 accuracy.
// This round: swapped-operand MFMA (A=W^T[n][k], B=data gathered straight into
// regs) -> LDS holds weights only (16.5KB vs 66KB), Y transpose via shfl.

typedef _Float16 f16;
typedef __attribute__((ext_vector_type(8))) _Float16 f16x8;
typedef __attribute__((ext_vector_type(4))) float f32x4;

__device__ __forceinline__ void glds16(const void* g, void* l) {
    __builtin_amdgcn_global_load_lds(
        (const __attribute__((address_space(1))) void*)g,
        (__attribute__((address_space(3))) void*)l, 16, 0, 0);
}

__device__ __forceinline__ uint32_t pk2(f16 a, f16 b) {
    union { f16 h[2]; uint32_t u; } x; x.h[0] = a; x.h[1] = b; return x.u;
}

// ---------------------------------------------------------------------------
// Legacy VALU MLP core: still used by the (small) encode_nodes kernel.
// ---------------------------------------------------------------------------
template<int ROWS, int K, int KP>
__device__ __forceinline__ void mlp_apply(
    const float* __restrict__ xs, float* __restrict__ hv,
    float* __restrict__ mu_s, float* __restrict__ rs_s,
    const float* __restrict__ W1, const float* __restrict__ b1,
    const float* __restrict__ W2, const float* __restrict__ b2,
    const float* __restrict__ g,  const float* __restrict__ be,
    float out[ROWS])
{
    const int t = threadIdx.x;
    float acc[ROWS];
    {
        const float bb = b1[t];
        #pragma unroll
        for (int r = 0; r < ROWS; r++) acc[r] = bb;
    }
    int k = 0;
    for (; k + 4 <= K; k += 4) {
        const float w0 = W1[(k + 0) * LNUM + t];
        const float w1 = W1[(k + 1) * LNUM + t];
        const float w2 = W1[(k + 2) * LNUM + t];
        const float w3 = W1[(k + 3) * LNUM + t];
        #pragma unroll
        for (int r = 0; r < ROWS; r++) {
            const float4 x = *(const float4*)(xs + r * KP + k);
            acc[r] = fmaf(x.x, w0, acc[r]);
            acc[r] = fmaf(x.y, w1, acc[r]);
            acc[r] = fmaf(x.z, w2, acc[r]);
            acc[r] = fmaf(x.w, w3, acc[r]);
        }
    }
    for (; k < K; ++k) {
        const float w = W1[k * LNUM + t];
        #pragma unroll
        for (int r = 0; r < ROWS; r++) acc[r] = fmaf(xs[r * KP + k], w, acc[r]);
    }
    #pragma unroll
    for (int r = 0; r < ROWS; r++) hv[r * LNUM + t] = fmaxf(acc[r], 0.f);
    __syncthreads();
    {
        const float bb = b2[t];
        #pragma unroll
        for (int r = 0; r < ROWS; r++) acc[r] = bb;
    }
    for (int k2 = 0; k2 < LNUM; k2 += 4) {
        const float w0 = W2[(k2 + 0) * LNUM + t];
        const float w1 = W2[(k2 + 1) * LNUM + t];
        const float w2 = W2[(k2 + 2) * LNUM + t];
        const float w3 = W2[(k2 + 3) * LNUM + t];
        #pragma unroll
        for (int r = 0; r < ROWS; r++) {
            const float4 x = *(const float4*)(hv + r * LNUM + k2);
            acc[r] = fmaf(x.x, w0, acc[r]);
            acc[r] = fmaf(x.y, w1, acc[r]);
            acc[r] = fmaf(x.z, w2, acc[r]);
            acc[r] = fmaf(x.w, w3, acc[r]);
        }
    }
    __syncthreads();
    #pragma unroll
    for (int r = 0; r < ROWS; r++) hv[r * LNUM + t] = fmaxf(acc[r], 0.f);
    __syncthreads();
    if (t < ROWS) {
        float s = 0.f, s2 = 0.f;
        for (int kk = 0; kk < LNUM; kk++) {
            const float v = hv[t * LNUM + kk];
            s += v; s2 += v * v;
        }
        const float m = s * (1.0f / LNUM);
        mu_s[t] = m;
        rs_s[t] = rsqrtf(fmaxf(s2 * (1.0f / LNUM) - m * m, 0.f) + 1e-5f);
    }
    __syncthreads();
    const float gg = g[t], bbe = be[t];
    #pragma unroll
    for (int r = 0; r < ROWS; r++)
        out[r] = fmaf(gg * (hv[r * LNUM + t] - mu_s[r]), rs_s[r], bbe);
}

__global__ __launch_bounds__(128) void encode_nodes_k(
    const float* __restrict__ u, const float* __restrict__ load_,
    const float* __restrict__ ntype,
    const float* __restrict__ W1, const float* __restrict__ b1,
    const float* __restrict__ W2, const float* __restrict__ b2,
    const float* __restrict__ g,  const float* __restrict__ be,
    float* __restrict__ nl)
{
    constexpr int ROWS = 4, K = 12, KP = 12;
    __shared__ __align__(16) float xs[ROWS * KP];
    __shared__ __align__(16) float hv[ROWS * LNUM];
    __shared__ float mu_s[ROWS], rs_s[ROWS];
    const int t = threadIdx.x;
    const int base = blockIdx.x * ROWS;
    if (t < ROWS * K) {
        const int r = t / K, k = t % K;
        const int n = base + r;
        float v;
        if (k < 2)      v = u[n * 2 + k];
        else if (k < 3) v = load_[n];
        else            v = ntype[n * 9 + (k - 3)];
        xs[r * KP + k] = v;
    }
    __syncthreads();
    float out[ROWS];
    mlp_apply<ROWS, K, KP>(xs, hv, mu_s, rs_s, W1, b1, W2, b2, g, be, out);
    #pragma unroll
    for (int r = 0; r < ROWS; r++) nl[(base + r) * LNUM + t] = out[r];
}

// ---------------------------------------------------------------------------
// Weight prep: f32 [S][K][128] -> f16 hi/lo tables transposed to [S][128][K].
// Includes the edge-encoder tables (K padded 5->32).
// ---------------------------------------------------------------------------
#define PE1 245760   // 5*384*128 (edge W1)
#define PE2 81920    // 5*128*128 (edge W2)
#define PN1 163840   // 5*256*128 (node W1)
#define PN2 81920    // 5*128*128 (node W2)
#define PQ1 4096     // 128*32    (enc-edge W1, k-padded)
#define PQ2 16384    // 128*128   (enc-edge W2)
#define PTOT (PE1+PE2+PN1+PN2+PQ1+PQ2)

__global__ __launch_bounds__(256) void prep_w_all_k(
    const float* __restrict__ eW1, const float* __restrict__ eW2,
    const float* __restrict__ nW1, const float* __restrict__ nW2,
    const float* __restrict__ qW1, const float* __restrict__ qW2,
    f16* __restrict__ out)
{
    int j = blockIdx.x * 256 + threadIdx.x;
    if (j >= PTOT) return;
    const float* W; int K, kreal; f16 *hi, *lo; f16* p = out;
    if (j < PE1) { W = eW1; K = 384; kreal = 384; hi = p; lo = p + PE1; }
    else { p += 2 * PE1; j -= PE1;
    if (j < PE2) { W = eW2; K = 128; kreal = 128; hi = p; lo = p + PE2; }
    else { p += 2 * PE2; j -= PE2;
    if (j < PN1) { W = nW1; K = 256; kreal = 256; hi = p; lo = p + PN1; }
    else { p += 2 * PN1; j -= PN1;
    if (j < PN2) { W = nW2; K = 128; kreal = 128; hi = p; lo = p + PN2; }
    else { p += 2 * PN2; j -= PN2;
    if (j < PQ1) { W = qW1; K = 32;  kreal = 5;   hi = p; lo = p + PQ1; }
    else { p += 2 * PQ1; j -= PQ1;
         { W = qW2; K = 128; kreal = 128; hi = p; lo = p + PQ2; } } } } } }
    const int k = j % K;
    const int rem = j / K;
    const int n = rem & 127;
    const int s = rem >> 7;
    const float v = (k < kreal) ? W[((size_t)s * kreal + k) * 128 + n] : 0.f;
    const f16 h = (f16)v;
    hi[j] = h;
    lo[j] = (f16)((v - (float)h) * 2048.f);
}

// ---------------------------------------------------------------------------
// Swapped-operand MFMA MLP. 256 threads = 4 waves; wave w owns rows
// [blk*64 + w*16, +16). A = W^T (prepped [n][k], LDS via global_load_lds with
// XOR swizzle o^=((o>>7)&3)<<4), B = data built in registers.
// MODE: 0 = edge block (gather nl[s],nl[r],el; residual el; atomic aggr)
//       1 = node block (nl, aggr; residual nl)
//       2 = edge encoder (computed features -> el)
// ---------------------------------------------------------------------------
template<int MODE, int NCH1, int K1S>
__global__ __launch_bounds__(256) void mfma_mlp_k(
    const float* __restrict__ in0, const float* __restrict__ in1,
    float* __restrict__ io, float* __restrict__ aggr,
    const int* __restrict__ senders, const int* __restrict__ receivers,
    const f16* __restrict__ W1h, const f16* __restrict__ W1l, const float* __restrict__ b1,
    const f16* __restrict__ W2h, const f16* __restrict__ W2l, const float* __restrict__ b2,
    const float* __restrict__ gam, const float* __restrict__ bet,
    int nrows)
{
    __shared__ __align__(16) f16 WH[4096];   // [128][32] f16, swizzled
    __shared__ __align__(16) f16 WL[4096];

    const int t  = threadIdx.x;
    const int w  = t >> 6;
    const int l  = t & 63;
    const int lr = l & 15;
    const int lg = l >> 4;
    const int swz = lg ^ ((lr >> 1) & 3);

    const int e    = blockIdx.x * 64 + w * 16 + lr;
    const int eidx = min(e, nrows - 1);

    int sv = 0, rv = 0;
    if constexpr (MODE != 1) { sv = senders[eidx]; rv = receivers[eidx]; }

    float feat[8];
    if constexpr (MODE == 2) {
        const float ax = in0[sv * 2], ay = in0[sv * 2 + 1];
        const float bx = in0[rv * 2], by = in0[rv * 2 + 1];
        const float rx = ax - bx, ry = ay - by;
        feat[0] = rx; feat[1] = ry; feat[2] = sqrtf(rx * rx + ry * ry);
        feat[3] = in1[sv * 2] - in1[rv * 2];
        feat[4] = in1[sv * 2 + 1] - in1[rv * 2 + 1];
        feat[5] = 0.f; feat[6] = 0.f; feat[7] = 0.f;
    }

    // stage one 32-wide K chunk of W (hi+lo) into LDS, swizzled, via glds.
    auto stage = [&](const f16* __restrict__ Wh, const f16* __restrict__ Wl,
                     const int kst, const int kc) {
        #pragma unroll
        for (int i = 0; i < 2; i++) {
            const int c = 2 * w + i;
            const int ophys = c * 1024 + l * 16;
            const int olog  = ophys ^ (((ophys >> 7) & 3) << 4);
            const int row   = olog >> 6;
            const int slot  = (olog >> 4) & 3;
            glds16(Wh + (size_t)row * kst + kc * 32 + slot * 8, (char*)WH + c * 1024);
            glds16(Wl + (size_t)row * kst + kc * 32 + slot * 8, (char*)WL + c * 1024);
        }
    };

    const f32x4 zero4 = {0.f, 0.f, 0.f, 0.f};
    f32x4 accH[8], accL[8];
    #pragma unroll
    for (int mf = 0; mf < 8; mf++) { accH[mf] = zero4; accL[mf] = zero4; }

    // ---------------- layer 1 ----------------
    for (int kc = 0; kc < NCH1; ++kc) {
        __syncthreads();
        stage(W1h, W1l, K1S, kc);
        float xv[8];
        if constexpr (MODE == 2) {
            #pragma unroll
            for (int j = 0; j < 8; j++) xv[j] = (lg == 0) ? feat[j] : 0.f;
        } else {
            const float* src;
            if constexpr (MODE == 0) {
                if (kc < 4)      src = in0 + (size_t)sv   * 128 + kc * 32 + lg * 8;
                else if (kc < 8) src = in0 + (size_t)rv   * 128 + (kc - 4) * 32 + lg * 8;
                else             src = in1 + (size_t)eidx * 128 + (kc - 8) * 32 + lg * 8;
            } else {
                if (kc < 4) src = in0 + (size_t)eidx * 128 + kc * 32 + lg * 8;
                else        src = in1 + (size_t)eidx * 128 + (kc - 4) * 32 + lg * 8;
            }
            const float4 x0 = *(const float4*)src;
            const float4 x1 = *(const float4*)(src + 4);
            xv[0] = x0.x; xv[1] = x0.y; xv[2] = x0.z; xv[3] = x0.w;
            xv[4] = x1.x; xv[5] = x1.y; xv[6] = x1.z; xv[7] = x1.w;
        }
        union { f16 h[8]; f16x8 v; } XH, XL;
        #pragma unroll
        for (int j = 0; j < 8; j++) {
            const f16 h = (f16)xv[j];
            XH.h[j] = h;
            XL.h[j] = (f16)((xv[j] - (float)h) * 2048.f);
        }
        __syncthreads();   // drains vmcnt -> weights + gathers complete
        #pragma unroll
        for (int mf = 0; mf < 8; mf++) {
            const int off = (mf * 16 + lr) * 64 + (swz << 4);
            const f16x8 wh = *(const f16x8*)((const char*)WH + off);
            const f16x8 wl = *(const f16x8*)((const char*)WL + off);
            accH[mf] = __builtin_amdgcn_mfma_f32_16x16x32_f16(wh, XH.v, accH[mf], 0, 0, 0);
            accL[mf] = __builtin_amdgcn_mfma_f32_16x16x32_f16(wh, XL.v, accL[mf], 0, 0, 0);
            accL[mf] = __builtin_amdgcn_mfma_f32_16x16x32_f16(wl, XH.v, accL[mf], 0, 0, 0);
        }
    }

    // layer-1 epilogue: bias+relu+split, all in registers.
    // lane holds h1[e][f], f = mf*16 + lg*4 + reg.
    uint32_t ypH[8][2], ypL[8][2];
    #pragma unroll
    for (int mf = 0; mf < 8; mf++) {
        const float4 bb = *(const float4*)(b1 + mf * 16 + lg * 4);
        const float bbr[4] = {bb.x, bb.y, bb.z, bb.w};
        f16 yh[4], yl[4];
        #pragma unroll
        for (int reg = 0; reg < 4; reg++) {
            float v = accH[mf][reg] + accL[mf][reg] * (1.f / 2048.f) + bbr[reg];
            v = fmaxf(v, 0.f);
            const f16 h = (f16)v;
            yh[reg] = h;
            yl[reg] = (f16)((v - (float)h) * 2048.f);
        }
        ypH[mf][0] = pk2(yh[0], yh[1]); ypH[mf][1] = pk2(yh[2], yh[3]);
        ypL[mf][0] = pk2(yl[0], yl[1]); ypL[mf][1] = pk2(yl[2], yl[3]);
        accH[mf] = zero4; accL[mf] = zero4;
    }

    // ---------------- layer 2 ----------------
    // B-frag lane (lg,lr) needs Y[e=w*16+lr][kc*32+lg*8+j]:
    //   j<4 from lane 32*(lg&1)+lr, j>=4 from +16; quad mf = kc*2+(lg>>1).
    const int src1 = ((l >> 4) & 1) * 32 + lr;
    const int src2 = src1 + 16;
    const bool hiSel = (l >= 32);
    #pragma unroll
    for (int kc = 0; kc < 4; ++kc) {
        __syncthreads();
        stage(W2h, W2l, 128, kc);
        union { uint32_t u[4]; f16x8 v; } BH, BL;
        {
            const uint32_t a0 = ypH[kc * 2][0],     a1 = ypH[kc * 2][1];
            const uint32_t c0 = ypH[kc * 2 + 1][0], c1 = ypH[kc * 2 + 1][1];
            const uint32_t s00 = __shfl((int)a0, src1), s01 = __shfl((int)a1, src1);
            const uint32_t s04 = __shfl((int)a0, src2), s05 = __shfl((int)a1, src2);
            const uint32_t u00 = __shfl((int)c0, src1), u01 = __shfl((int)c1, src1);
            const uint32_t u04 = __shfl((int)c0, src2), u05 = __shfl((int)c1, src2);
            BH.u[0] = hiSel ? u00 : s00; BH.u[1] = hiSel ? u01 : s01;
            BH.u[2] = hiSel ? u04 : s04; BH.u[3] = hiSel ? u05 : s05;
        }
        {
            const uint32_t a0 = ypL[kc * 2][0],     a1 = ypL[kc * 2][1];
            const uint32_t c0 = ypL[kc * 2 + 1][0], c1 = ypL[kc * 2 + 1][1];
            const uint32_t s00 = __shfl((int)a0, src1), s01 = __shfl((int)a1, src1);
            const uint32_t s04 = __shfl((int)a0, src2), s05 = __shfl((int)a1, src2);
            const uint32_t u00 = __shfl((int)c0, src1), u01 = __shfl((int)c1, src1);
            const uint32_t u04 = __shfl((int)c0, src2), u05 = __shfl((int)c1, src2);
            BL.u[0] = hiSel ? u00 : s00; BL.u[1] = hiSel ? u01 : s01;
            BL.u[2] = hiSel ? u04 : s04; BL.u[3] = hiSel ? u05 : s05;
        }
        __syncthreads();
        #pragma unroll
        for (int mf = 0; mf < 8; mf++) {
            const int off = (mf * 16 + lr) * 64 + (swz << 4);
            const f16x8 wh = *(const f16x8*)((const char*)WH + off);
            const f16x8 wl = *(const f16x8*)((const char*)WL + off);
            accH[mf] = __builtin_amdgcn_mfma_f32_16x16x32_f16(wh, BH.v, accH[mf], 0, 0, 0);
            accL[mf] = __builtin_amdgcn_mfma_f32_16x16x32_f16(wh, BL.v, accL[mf], 0, 0, 0);
            accL[mf] = __builtin_amdgcn_mfma_f32_16x16x32_f16(wl, BH.v, accL[mf], 0, 0, 0);
        }
    }

    // layer-2 epilogue: bias+relu+LN (2 shfl_xor) + residual / scatter.
    float vv[8][4];
    float s1 = 0.f, s2 = 0.f;
    #pragma unroll
    for (int mf = 0; mf < 8; mf++) {
        const float4 bb = *(const float4*)(b2 + mf * 16 + lg * 4);
        const float bbr[4] = {bb.x, bb.y, bb.z, bb.w};
        #pragma unroll
        for (int reg = 0; reg < 4; reg++) {
            float v = accH[mf][reg] + accL[mf][reg] * (1.f / 2048.f) + bbr[reg];
            v = fmaxf(v, 0.f);
            vv[mf][reg] = v;
            s1 += v; s2 += v * v;
        }
    }
    s1 += __shfl_xor(s1, 16); s2 += __shfl_xor(s2, 16);
    s1 += __shfl_xor(s1, 32); s2 += __shfl_xor(s2, 32);
    const float mu = s1 * (1.f / 128.f);
    const float rs = rsqrtf(fmaxf(s2 * (1.f / 128.f) - mu * mu, 0.f) + 1e-5f);

    if (e < nrows) {
        #pragma unroll
        for (int mf = 0; mf < 8; mf++) {
            const float4 gv = *(const float4*)(gam + mf * 16 + lg * 4);
            const float4 bv = *(const float4*)(bet + mf * 16 + lg * 4);
            const float gr[4] = {gv.x, gv.y, gv.z, gv.w};
            const float br[4] = {bv.x, bv.y, bv.z, bv.w};
            float o[4];
            #pragma unroll
            for (int reg = 0; reg < 4; reg++)
                o[reg] = gr[reg] * (vv[mf][reg] - mu) * rs + br[reg];
            float* dst = io + (size_t)e * 128 + mf * 16 + lg * 4;
            if constexpr (MODE == 2) {
                float4 ov = {o[0], o[1], o[2], o[3]};
                *(float4*)dst = ov;
            } else {
                float4 cur = *(const float4*)dst;
                cur.x += o[0]; cur.y += o[1]; cur.z += o[2]; cur.w += o[3];
                *(float4*)dst = cur;
                if constexpr (MODE == 0) {
                    float* ap = aggr + (size_t)rv * 128 + mf * 16 + lg * 4;
                    #pragma unroll
                    for (int reg = 0; reg < 4; reg++) atomicAdd(ap + reg, o[reg]);
                }
            }
        }
    }
}

// Decoder -> FLOAT32 output, layout [TW, N, TD].
__global__ __launch_bounds__(128) void decode_k(
    const float* __restrict__ nl,
    const float* __restrict__ W1, const float* __restrict__ b1,
    const float* __restrict__ W2, const float* __restrict__ b2,
    float* __restrict__ out)
{
    constexpr int NPB = 16;
    __shared__ __align__(16) float xs[NPB * LNUM];
    __shared__ float hh[NPB * 8];
    const int t = threadIdx.x;
    const int base = blockIdx.x * NPB;
    for (int r = 0; r < NPB; r++) xs[r * LNUM + t] = nl[(base + r) * LNUM + t];
    __syncthreads();
    {
        const int node = t >> 3, j = t & 7;
        float a = b1[j];
        for (int k = 0; k < LNUM; k++) a = fmaf(xs[node * LNUM + k], W1[k * 8 + j], a);
        hh[node * 8 + j] = a / (1.f + expf(-a));
    }
    __syncthreads();
    for (int idx = t; idx < NPB * 10; idx += 128) {
        const int node = idx / 10, c = idx % 10;
        float a = b2[c];
        #pragma unroll
        for (int j = 0; j < 8; j++) a = fmaf(hh[node * 8 + j], W2[j * 10 + c], a);
        const int tt = c >> 1, d = c & 1;
        out[(size_t)tt * (NNODES * 2) + (size_t)(base + node) * 2 + d] =
            a * (float)(tt + 1);
    }
}

__global__ __launch_bounds__(256) void zero_k(float* __restrict__ p, int n)
{
    const int i = blockIdx.x * 256 + threadIdx.x;
    if (i < n) p[i] = 0.f;
}

// ---------------------------------------------------------------------------
extern "C" void kernel_launch(void* const* d_in, const int* in_sizes, int n_in,
                              void* d_out, int out_size, void* d_ws, size_t ws_size,
                              hipStream_t stream) {
    const float* F[34];
    for (int i = 0; i < 34; i++) F[i] = (const float*)d_in[i];
    const int* senders   = (const int*)d_in[4];
    const int* receivers = (const int*)d_in[5];

    const size_t nN = (size_t)NNODES * LNUM;
    const size_t nE = (size_t)NEDGES * LNUM;
    float* nl   = (float*)d_ws;
    float* el   = nl + nN;
    float* aggr = el + nE;
    f16* wb = (f16*)(aggr + nN);
    f16 *eW1h = wb,          *eW1l = eW1h + PE1;
    f16 *eW2h = eW1l + PE1,  *eW2l = eW2h + PE2;
    f16 *nW1h = eW2l + PE2,  *nW1l = nW1h + PN1;
    f16 *nW2h = nW1l + PN1,  *nW2l = nW2h + PN2;
    f16 *qW1h = nW2l + PN2,  *qW1l = qW1h + PQ1;
    f16 *qW2h = qW1l + PQ1,  *qW2l = qW2h + PQ2;

    prep_w_all_k<<<(PTOT + 255) / 256, 256, 0, stream>>>(
        F[18], F[20], F[24], F[26], F[12], F[14], wb);

    encode_nodes_k<<<NNODES / 4, 128, 0, stream>>>(
        F[2], F[3], F[1], F[6], F[7], F[8], F[9], F[10], F[11], nl);

    const int egrid = (NEDGES + 63) / 64;   // 2344
    const int ngrid = (NNODES + 63) / 64;   // 469

    // edge encoder (MFMA, computed features)
    mfma_mlp_k<2, 1, 32><<<egrid, 256, 0, stream>>>(
        F[0], F[2], el, nullptr, senders, receivers,
        qW1h, qW1l, F[13], qW2h, qW2l, F[15], F[16], F[17], NEDGES);

    for (int s = 0; s < NSTEPS; s++) {
        zero_k<<<(NNODES * LNUM + 255) / 256, 256, 0, stream>>>(aggr, NNODES * LNUM);
        mfma_mlp_k<0, 12, 384><<<egrid, 256, 0, stream>>>(
            nl, el, el, aggr, senders, receivers,
            eW1h + (size_t)s * 384 * 128, eW1l + (size_t)s * 384 * 128, F[19] + s * LNUM,
            eW2h + (size_t)s * 128 * 128, eW2l + (size_t)s * 128 * 128, F[21] + s * LNUM,
            F[22] + s * LNUM, F[23] + s * LNUM, NEDGES);
        mfma_mlp_k<1, 8, 256><<<ngrid, 256, 0, stream>>>(
            nl, aggr, nl, nullptr, nullptr, nullptr,
            nW1h + (size_t)s * 256 * 128, nW1l + (size_t)s * 256 * 128, F[25] + s * LNUM,
            nW2h + (size_t)s * 128 * 128, nW2l + (size_t)s * 128 * 128, F[27] + s * LNUM,
            F[28] + s * LNUM, F[29] + s * LNUM, NNODES);
    }

    decode_k<<<NNODES / 16, 128, 0, stream>>>(
        nl, F[30], F[31], F[32], F[33], (float*)d_out);
}